// Round 3
// baseline (550.706 us; speedup 1.0000x reference)
//
#include <hip/hip_runtime.h>

typedef __attribute__((ext_vector_type(8))) short bf16x8;
typedef __attribute__((ext_vector_type(4))) float f32x4;

#define UR _Pragma("unroll")

__device__ __forceinline__ float bf2f(unsigned short u) {
    union { unsigned int i; float f; } v; v.i = ((unsigned int)u) << 16; return v.f;
}
__device__ __forceinline__ unsigned short f2bf(float f) {
    union { float f; unsigned int i; } v; v.f = f;
    unsigned int u = v.i;
    return (unsigned short)((u + 0x7FFFu + ((u >> 16) & 1u)) >> 16);
}
__device__ __forceinline__ uint2 pack4(f32x4 x) {
    uint2 o;
    o.x = (unsigned int)f2bf(x[0]) | ((unsigned int)f2bf(x[1]) << 16);
    o.y = (unsigned int)f2bf(x[2]) | ((unsigned int)f2bf(x[3]) << 16);
    return o;
}
// XOR-swizzled byte address into a [rows][256 bf16] LDS tile (512 B rows)
__device__ __forceinline__ int swz(int r, int c) {
    return r * 512 + (c ^ ((r & 7) << 4));
}

// ---------------- weight prep: fp32 [l][k][n] -> bf16 [branch][l][n][k] ----------------
// LDS 64x64 tile transpose: coalesced reads AND coalesced writes.
__global__ __launch_bounds__(256)
void prep_kernel(const float* __restrict__ lw1, const float* __restrict__ rw1,
                 const float* __restrict__ lw2, const float* __restrict__ rw2,
                 unsigned short* __restrict__ w1t, unsigned short* __restrict__ w2t)
{
    __shared__ unsigned short T[64][68];   // [n][k], +4 pad
    int bid = blockIdx.x;                  // 192 = 12 matrices x 16 tiles
    int mat = bid >> 4;                    // tensor*3 + l
    int tile = bid & 15;
    int tensor = mat / 3;                  // 0:lw1 1:rw1 2:lw2 3:rw2
    int l = mat - tensor * 3;
    int k0 = (tile >> 2) * 64, n0 = (tile & 3) * 64;
    const float* src = (tensor == 0) ? lw1 : (tensor == 1) ? rw1 : (tensor == 2) ? lw2 : rw2;
    unsigned short* dst = ((tensor < 2) ? w1t : w2t) + (tensor & 1) * 196608;

    int tx = threadIdx.x & 63, ty = threadIdx.x >> 6;
    UR for (int p = 0; p < 16; ++p) {
        int k = k0 + p * 4 + ty;
        T[tx][k - k0] = f2bf(src[l * 65536 + k * 256 + n0 + tx]);
    }
    __syncthreads();
    UR for (int p = 0; p < 16; ++p) {
        int n = n0 + p * 4 + ty;
        dst[l * 65536 + n * 256 + k0 + tx] = T[n - n0][tx];
    }
}

// ---------------- conv: 8 output rows per thread, 24-row sweep, XCD-contiguous ----------------
__global__ __launch_bounds__(256, 4)
void conv_kernel(const float* __restrict__ inp,
                 const float* __restrict__ lpad, const float* __restrict__ rpad,
                 const float* __restrict__ lwt, const float* __restrict__ rwt,
                 uint2* __restrict__ wsL, uint2* __restrict__ wsR)
{
    int raw = blockIdx.x;                    // 1024
    int w = (raw & 7) * 128 + (raw >> 3);    // XCD-contiguous chunks
    int t = threadIdx.x;
    int q = t & 63;                          // channel quad 0..63
    int g = t >> 6;                          // row-group 0..3 (wave-uniform)
    int R0 = w * 32 + g * 8;                 // first output row (multiple of 8)
    int s0 = R0 & 2047;                      // in-batch offset
    int c = q * 4;

    float wl[9], wr[9];
    UR for (int j = 0; j < 9; ++j) { wl[j] = lwt[j]; wr[j] = rwt[j]; }

    f32x4 aL[8], aR[8];
    UR for (int k = 0; k < 8; ++k) {
        aL[k] = (f32x4){0.f, 0.f, 0.f, 0.f};
        aR[k] = (f32x4){0.f, 0.f, 0.f, 0.f};
    }
    UR for (int i = -8; i <= 15; ++i) {
        int si = s0 + i;
        const float* src;
        if (si < 0)          src = lpad + (si + 8) * 256 + c;
        else if (si >= 2048) src = rpad + (si - 2048) * 256 + c;
        else                 src = inp + (size_t)(R0 + i) * 256 + c;
        f32x4 v = *(const f32x4*)src;
        UR for (int k = 0; k < 8; ++k) {
            int j = i - k;
            if (j >= -8 && j <= 0) aL[k] += v * wl[j + 8];
            if (j >= 0 && j <= 8)  aR[k] += v * wr[j];
        }
    }
    UR for (int k = 0; k < 8; ++k) {
        int idx = (R0 + k) * 64 + q;
        wsL[idx] = pack4(aL[k]);
        wsR[idx] = pack4(aR[k]);
    }
}

// ---------------- fused 3-layer FFN stack: 32 rows x 256 feats per block ----------------
__global__ __launch_bounds__(256, 4)
void mega_kernel(const unsigned short* __restrict__ convbf,   // [2][32768][256] bf16
                 const unsigned short* __restrict__ w1t,      // [2][3][256][256] bf16 (n-major)
                 const unsigned short* __restrict__ w2t,
                 const float* __restrict__ b1L, const float* __restrict__ b1R,
                 const float* __restrict__ b2L, const float* __restrict__ b2R,
                 const float* __restrict__ gL,  const float* __restrict__ gR,
                 const float* __restrict__ bbL, const float* __restrict__ bbR,
                 float* __restrict__ out)
{
    __shared__ unsigned short YH[32 * 256];  // 16 KB, Y then H alternately
    __shared__ float red[4][32][2];          // 1 KB, LN cross-wave partials

    const int t = threadIdx.x;
    const int wm = t >> 6;       // wave = feature 64-chunk 0..3
    const int ln = t & 63;
    const int lr = ln & 15;
    const int lh = ln >> 4;

    const int raw = blockIdx.x;                  // 2048
    const int w = (raw & 7) * 256 + (raw >> 3);  // XCD-contiguous
    const int br = w >> 10;                      // branch
    const int tile = w & 1023;
    const int r0 = tile * 32;

    const unsigned short* cv  = convbf + (size_t)br * (32768u * 256u);
    const unsigned short* W1b = w1t + (size_t)br * 196608;
    const unsigned short* W2b = w2t + (size_t)br * 196608;
    const float* B1 = br ? b1R : b1L;
    const float* B2 = br ? b2R : b2L;
    const float* G  = br ? gR  : gL;
    const float* Bb = br ? bbR : bbL;

    int rr[2], dd[4], hh[4];
    UR for (int n = 0; n < 2; ++n) rr[n] = n * 16 + lr;                 // sample row (C col)
    UR for (int m = 0; m < 4; ++m) dd[m] = wm * 64 + m * 16 + lh * 4;   // feature dim
    UR for (int m = 0; m < 4; ++m) hh[m] = wm * 64 + m * 16 + lr;       // A-frag row

    // residual x^T fragments (fp32) from bf16 conv output
    f32x4 x[4][2];
    UR for (int m = 0; m < 4; ++m)
      UR for (int n = 0; n < 2; ++n) {
        uint2 raw2 = *(const uint2*)(cv + (size_t)(r0 + rr[n]) * 256 + dd[m]);
        f32x4 v;
        v[0] = bf2f((unsigned short)(raw2.x & 0xffffu));
        v[1] = bf2f((unsigned short)(raw2.x >> 16));
        v[2] = bf2f((unsigned short)(raw2.y & 0xffffu));
        v[3] = bf2f((unsigned short)(raw2.y >> 16));
        x[m][n] = v;
      }

    for (int lay = 0; lay < 3; ++lay) {
        // ------- LayerNorm stats -------
        UR for (int n = 0; n < 2; ++n) {
            float s = 0.f, q = 0.f;
            UR for (int m = 0; m < 4; ++m)
              UR for (int r = 0; r < 4; ++r) { float v = x[m][n][r]; s += v; q += v * v; }
            s += __shfl_xor(s, 16); q += __shfl_xor(q, 16);
            s += __shfl_xor(s, 32); q += __shfl_xor(q, 32);
            if (lh == 0) {
                red[wm][n * 16 + lr][0] = s;
                red[wm][n * 16 + lr][1] = q;
            }
        }
        __syncthreads();
        float mean[2], rstd[2];
        UR for (int n = 0; n < 2; ++n) {
            int row = n * 16 + lr;
            float S = 0.f, Q = 0.f;
            UR for (int u = 0; u < 4; ++u) { S += red[u][row][0]; Q += red[u][row][1]; }
            float mu = S * (1.f / 256.f);
            float var = Q * (1.f / 256.f) - mu * mu;
            mean[n] = mu;
            rstd[n] = rsqrtf(var + 1e-6f);
        }
        f32x4 gf[4], bfr_[4];
        UR for (int m = 0; m < 4; ++m) {
            gf[m]   = *(const f32x4*)(G  + lay * 256 + dd[m]);
            bfr_[m] = *(const f32x4*)(Bb + lay * 256 + dd[m]);
        }
        UR for (int m = 0; m < 4; ++m)
          UR for (int n = 0; n < 2; ++n) {
            f32x4 y;
            UR for (int r = 0; r < 4; ++r)
                y[r] = (x[m][n][r] - mean[n]) * rstd[n] * gf[m][r] + bfr_[m][r];
            *(uint2*)((char*)YH + swz(rr[n], dd[m] * 2)) = pack4(y);
          }
        __syncthreads();    // Y ready

        // ------- GEMM1: C1^T = W1T · Y^T -------
        const unsigned short* Wl = W1b + lay * 65536;
        f32x4 acc[4][2];
        UR for (int m = 0; m < 4; ++m)
          UR for (int n = 0; n < 2; ++n) acc[m][n] = (f32x4){0.f, 0.f, 0.f, 0.f};
        UR for (int kk = 0; kk < 8; ++kk) {
            bf16x8 a[4], b[2];
            UR for (int m = 0; m < 4; ++m)
                a[m] = *(const bf16x8*)(Wl + hh[m] * 256 + kk * 32 + lh * 8);
            UR for (int n = 0; n < 2; ++n)
                b[n] = *(const bf16x8*)((const char*)YH + swz(rr[n], kk * 64 + lh * 16));
            UR for (int m = 0; m < 4; ++m)
              UR for (int n = 0; n < 2; ++n)
                acc[m][n] = __builtin_amdgcn_mfma_f32_16x16x32_bf16(a[m], b[n], acc[m][n], 0, 0, 0);
        }
        f32x4 b1f[4];
        UR for (int m = 0; m < 4; ++m) b1f[m] = *(const f32x4*)(B1 + lay * 256 + dd[m]);
        __syncthreads();    // all waves done reading Y
        UR for (int m = 0; m < 4; ++m)
          UR for (int n = 0; n < 2; ++n) {
            f32x4 h;
            UR for (int r = 0; r < 4; ++r) h[r] = fmaxf(acc[m][n][r] + b1f[m][r], 0.f);
            *(uint2*)((char*)YH + swz(rr[n], dd[m] * 2)) = pack4(h);
          }
        __syncthreads();    // H ready

        // ------- GEMM2: C2^T = W2T · H^T -------
        const unsigned short* W2l = W2b + lay * 65536;
        UR for (int m = 0; m < 4; ++m)
          UR for (int n = 0; n < 2; ++n) acc[m][n] = (f32x4){0.f, 0.f, 0.f, 0.f};
        UR for (int kk = 0; kk < 8; ++kk) {
            bf16x8 a[4], b[2];
            UR for (int m = 0; m < 4; ++m)
                a[m] = *(const bf16x8*)(W2l + hh[m] * 256 + kk * 32 + lh * 8);
            UR for (int n = 0; n < 2; ++n)
                b[n] = *(const bf16x8*)((const char*)YH + swz(rr[n], kk * 64 + lh * 16));
            UR for (int m = 0; m < 4; ++m)
              UR for (int n = 0; n < 2; ++n)
                acc[m][n] = __builtin_amdgcn_mfma_f32_16x16x32_bf16(a[m], b[n], acc[m][n], 0, 0, 0);
        }
        f32x4 b2f[4];
        UR for (int m = 0; m < 4; ++m) b2f[m] = *(const f32x4*)(B2 + lay * 256 + dd[m]);
        UR for (int m = 0; m < 4; ++m)
          UR for (int n = 0; n < 2; ++n)
            UR for (int r = 0; r < 4; ++r)
                x[m][n][r] += acc[m][n][r] + b2f[m][r];

        // ------- store layer output (and duplicate final) -------
        float* outL = out + ((size_t)lay * 32768 + r0) * 512 + br * 256;
        UR for (int m = 0; m < 4; ++m)
          UR for (int n = 0; n < 2; ++n) {
            float* p = outL + (size_t)rr[n] * 512 + dd[m];
            *(f32x4*)p = x[m][n];
            if (lay == 2) *(f32x4*)(p + 16777216) = x[m][n];
          }
    }
}

extern "C" void kernel_launch(void* const* d_in, const int* in_sizes, int n_in,
                              void* d_out, int out_size, void* d_ws, size_t ws_size,
                              hipStream_t stream)
{
    const float* inputs = (const float*)d_in[0];
    const float* lpad = (const float*)d_in[1];
    const float* rpad = (const float*)d_in[2];
    const float* lwt  = (const float*)d_in[3];
    const float* rwt  = (const float*)d_in[4];
    const float* lw1  = (const float*)d_in[5];
    const float* lb1  = (const float*)d_in[6];
    const float* lw2  = (const float*)d_in[7];
    const float* lb2  = (const float*)d_in[8];
    const float* lg   = (const float*)d_in[9];
    const float* lbb  = (const float*)d_in[10];
    const float* rw1  = (const float*)d_in[11];
    const float* rb1  = (const float*)d_in[12];
    const float* rw2  = (const float*)d_in[13];
    const float* rb2  = (const float*)d_in[14];
    const float* rg   = (const float*)d_in[15];
    const float* rbb  = (const float*)d_in[16];

    char* ws = (char*)d_ws;
    // ws map (bytes): [0, 16M) convL bf16 | [16M, 32M) convR bf16 | w1t | w2t
    unsigned short* convb = (unsigned short*)ws;
    unsigned short* w1t   = (unsigned short*)(ws + 33554432);
    unsigned short* w2t   = (unsigned short*)(ws + 33554432 + 786432);

    prep_kernel<<<192, 256, 0, stream>>>(lw1, rw1, lw2, rw2, w1t, w2t);
    conv_kernel<<<1024, 256, 0, stream>>>(inputs, lpad, rpad, lwt, rwt,
                                          (uint2*)convb, (uint2*)(convb + 32768u * 256u));
    mega_kernel<<<2048, 256, 0, stream>>>(convb, w1t, w2t,
                                          lb1, rb1, lb2, rb2, lg, rg, lbb, rbb,
                                          (float*)d_out);
}

// Round 4
// 441.408 us; speedup vs baseline: 1.2476x; 1.2476x over previous
//
#include <hip/hip_runtime.h>

typedef __attribute__((ext_vector_type(8))) short bf16x8;
typedef __attribute__((ext_vector_type(4))) float f32x4;

#define UR _Pragma("unroll")
#define LGKM0 asm volatile("s_waitcnt lgkmcnt(0)" ::: "memory")
#define BARRIER do { LGKM0; __builtin_amdgcn_s_barrier(); } while (0)
#define WAITV2  asm volatile("s_waitcnt vmcnt(2)" ::: "memory")
#define WAITV10 asm volatile("s_waitcnt vmcnt(10)" ::: "memory")
#define WAITV0  asm volatile("s_waitcnt vmcnt(0)" ::: "memory")

__device__ __forceinline__ float bf2f(unsigned short u) {
    union { unsigned int i; float f; } v; v.i = ((unsigned int)u) << 16; return v.f;
}
__device__ __forceinline__ unsigned short f2bf(float f) {
    union { float f; unsigned int i; } v; v.f = f;
    unsigned int u = v.i;
    return (unsigned short)((u + 0x7FFFu + ((u >> 16) & 1u)) >> 16);
}
__device__ __forceinline__ uint2 pack4(f32x4 x) {
    uint2 o;
    o.x = (unsigned int)f2bf(x[0]) | ((unsigned int)f2bf(x[1]) << 16);
    o.y = (unsigned int)f2bf(x[2]) | ((unsigned int)f2bf(x[3]) << 16);
    return o;
}
// XOR-swizzled byte address into a [rows][256 bf16] LDS tile (512 B rows)
__device__ __forceinline__ int swz(int r, int c) {
    return r * 512 + (c ^ ((r & 7) << 4));
}

// ---- weight prep: fp32 [l][k][n] -> bf16 MFMA-staged slice stream ----
// wstream[br][S][f], S = lay*16 + G*8 + s (G: 0=W1,1=W2), slice = 8192 bf16.
// f = ((grp*4 + lh)*16 + lr)*8 + e ; n = grp*16+lr ; k = s*32 + lh*8 + e.
__global__ __launch_bounds__(256)
void prep_kernel(const float* __restrict__ lw1, const float* __restrict__ rw1,
                 const float* __restrict__ lw2, const float* __restrict__ rw2,
                 unsigned short* __restrict__ wstream)
{
    __shared__ float T[8192];              // [k_local 0..31][n 0..255]
    int bid = blockIdx.x;                  // 96 = br*48 + lay*16 + G*8 + s
    int s = bid & 7, G = (bid >> 3) & 1, lay = (bid >> 4) % 3, br = bid / 48;
    const float* src = (G == 0) ? (br ? rw1 : lw1) : (br ? rw2 : lw2);
    src += lay * 65536 + s * 8192;
    int t = threadIdx.x;
    UR for (int i = 0; i < 32; ++i) T[i * 256 + t] = src[i * 256 + t];
    __syncthreads();
    int S = lay * 16 + G * 8 + s;
    unsigned short* dst = wstream + (size_t)br * 393216 + S * 8192 + t * 32;
    UR for (int c = 0; c < 4; ++c) {
        unsigned int wv[4];
        UR for (int h = 0; h < 4; ++h) {
            unsigned short e2[2];
            UR for (int z = 0; z < 2; ++z) {
                int f = t * 32 + c * 8 + h * 2 + z;
                int grp = f >> 9, lh = (f >> 7) & 3, lr = (f >> 3) & 15, e = f & 7;
                int n = grp * 16 + lr, kl = lh * 8 + e;
                e2[z] = f2bf(T[kl * 256 + n]);
            }
            wv[h] = (unsigned int)e2[0] | ((unsigned int)e2[1] << 16);
        }
        uint4 v; v.x = wv[0]; v.y = wv[1]; v.z = wv[2]; v.w = wv[3];
        *(uint4*)(dst + c * 8) = v;
    }
}

// ---- conv: 8 output rows per thread, 24-row sweep, XCD-contiguous ----
__global__ __launch_bounds__(256, 4)
void conv_kernel(const float* __restrict__ inp,
                 const float* __restrict__ lpad, const float* __restrict__ rpad,
                 const float* __restrict__ lwt, const float* __restrict__ rwt,
                 uint2* __restrict__ wsL, uint2* __restrict__ wsR)
{
    int raw = blockIdx.x;                    // 1024
    int w = (raw & 7) * 128 + (raw >> 3);    // XCD-contiguous chunks
    int t = threadIdx.x;
    int q = t & 63;
    int g = t >> 6;
    int R0 = w * 32 + g * 8;
    int s0 = R0 & 2047;
    int c = q * 4;

    float wl[9], wr[9];
    UR for (int j = 0; j < 9; ++j) { wl[j] = lwt[j]; wr[j] = rwt[j]; }

    f32x4 aL[8], aR[8];
    UR for (int k = 0; k < 8; ++k) {
        aL[k] = (f32x4){0.f, 0.f, 0.f, 0.f};
        aR[k] = (f32x4){0.f, 0.f, 0.f, 0.f};
    }
    UR for (int i = -8; i <= 15; ++i) {
        int si = s0 + i;
        const float* src;
        if (si < 0)          src = lpad + (si + 8) * 256 + c;
        else if (si >= 2048) src = rpad + (si - 2048) * 256 + c;
        else                 src = inp + (size_t)(R0 + i) * 256 + c;
        f32x4 v = *(const f32x4*)src;
        UR for (int k = 0; k < 8; ++k) {
            int j = i - k;
            if (j >= -8 && j <= 0) aL[k] += v * wl[j + 8];
            if (j >= 0 && j <= 8)  aR[k] += v * wr[j];
        }
    }
    UR for (int k = 0; k < 8; ++k) {
        int idx = (R0 + k) * 64 + q;
        wsL[idx] = pack4(aL[k]);
        wsR[idx] = pack4(aR[k]);
    }
}

// ---- fused 3-layer FFN stack, weight-stream pipelined through LDS ----
__device__ __forceinline__ void stage_slice(const unsigned short* g, unsigned short* l, int t) {
    __builtin_amdgcn_global_load_lds(
        (const __attribute__((address_space(1))) unsigned int*)(g + t * 8),
        (__attribute__((address_space(3))) unsigned int*)(l + t * 8), 16, 0, 0);
    __builtin_amdgcn_global_load_lds(
        (const __attribute__((address_space(1))) unsigned int*)(g + 4096 + t * 8),
        (__attribute__((address_space(3))) unsigned int*)(l + 4096 + t * 8), 16, 0, 0);
}

__global__ __launch_bounds__(512, 4)
void mega_kernel(const unsigned short* __restrict__ convbf,   // [2][32768][256] bf16
                 const unsigned short* __restrict__ wstream,  // [2][48][8192] bf16
                 const float* __restrict__ b1L, const float* __restrict__ b1R,
                 const float* __restrict__ b2L, const float* __restrict__ b2R,
                 const float* __restrict__ gL,  const float* __restrict__ gR,
                 const float* __restrict__ bbL, const float* __restrict__ bbR,
                 float* __restrict__ out)
{
    __shared__ unsigned short Ybuf[64 * 256];   // 32 KB activation tile (swizzled rows)
    __shared__ unsigned short WSH[2 * 8192];    // 2 x 16 KB weight-slice double buffer
    __shared__ float red[4][64][2];             // 2 KB LN partials

    const int t = threadIdx.x;
    const int wv2 = t >> 6;
    const int ln = t & 63;
    const int lr = ln & 15;
    const int lh = ln >> 4;
    const int wm = wv2 >> 1;     // feature 64-chunk 0..3
    const int wn = wv2 & 1;      // row-half 0..1

    const int raw = blockIdx.x;                  // 1024
    const int w = (raw & 7) * 128 + (raw >> 3);  // XCD-contiguous
    const int br = w >> 9;
    const int r0 = (w & 511) * 64;

    const unsigned short* cv  = convbf + (size_t)br * (32768u * 256u);
    const unsigned short* Wst = wstream + (size_t)br * 393216;
    const float* B1 = br ? b1R : b1L;
    const float* B2 = br ? b2R : b2L;
    const float* G  = br ? gR  : gL;
    const float* Bb = br ? bbR : bbL;

    int rr[2], dd[4], aoff[4];
    UR for (int n = 0; n < 2; ++n) rr[n] = wn * 32 + n * 16 + lr;
    UR for (int m = 0; m < 4; ++m) dd[m] = wm * 64 + m * 16 + lh * 4;
    UR for (int m = 0; m < 4; ++m) aoff[m] = ((wm * 4 + m) * 64 + ln) * 8;

    // residual x (issue loads first, then stage slice 0 so x-wait leaves it in flight)
    f32x4 x[4][2];
    UR for (int m = 0; m < 4; ++m)
      UR for (int n = 0; n < 2; ++n) {
        uint2 rw2_ = *(const uint2*)(cv + (size_t)(r0 + rr[n]) * 256 + dd[m]);
        f32x4 v;
        v[0] = bf2f((unsigned short)(rw2_.x & 0xffffu));
        v[1] = bf2f((unsigned short)(rw2_.x >> 16));
        v[2] = bf2f((unsigned short)(rw2_.y & 0xffffu));
        v[3] = bf2f((unsigned short)(rw2_.y >> 16));
        x[m][n] = v;
      }
    stage_slice(Wst, WSH, t);   // slice 0 -> buf 0

    for (int lay = 0; lay < 3; ++lay) {
        // LN gains/biases + stats (x in regs; red write, no barrier yet)
        f32x4 gf[4], bfr_[4];
        UR for (int m = 0; m < 4; ++m) {
            gf[m]   = *(const f32x4*)(G  + lay * 256 + dd[m]);
            bfr_[m] = *(const f32x4*)(Bb + lay * 256 + dd[m]);
        }
        UR for (int n = 0; n < 2; ++n) {
            float s = 0.f, q = 0.f;
            UR for (int m = 0; m < 4; ++m)
              UR for (int r = 0; r < 4; ++r) { float v = x[m][n][r]; s += v; q += v * v; }
            s += __shfl_xor(s, 16); q += __shfl_xor(q, 16);
            s += __shfl_xor(s, 32); q += __shfl_xor(q, 32);
            if (lh == 0) {
                red[wm][rr[n]][0] = s;
                red[wm][rr[n]][1] = q;
            }
        }

        f32x4 acc[4][2];
        UR for (int m = 0; m < 4; ++m)
          UR for (int n = 0; n < 2; ++n) acc[m][n] = (f32x4){0.f, 0.f, 0.f, 0.f};

        // ---------- GEMM1: 8 weight slices ----------
        UR for (int kk = 0; kk < 8; ++kk) {
            int S = lay * 16 + kk;
            BARRIER;                                           // (a) prev reads done, red visible
            stage_slice(Wst + (S + 1) * 8192, WSH + ((S + 1) & 1) * 8192, t);
            if (kk == 0) {
                // LN epilogue: finish stats, write Y
                float mean[2], rstd[2];
                UR for (int n = 0; n < 2; ++n) {
                    float Ssum = 0.f, Q = 0.f;
                    UR for (int u = 0; u < 4; ++u) { Ssum += red[u][rr[n]][0]; Q += red[u][rr[n]][1]; }
                    float mu = Ssum * (1.f / 256.f);
                    mean[n] = mu;
                    rstd[n] = rsqrtf(Q * (1.f / 256.f) - mu * mu + 1e-6f);
                }
                UR for (int m = 0; m < 4; ++m)
                  UR for (int n = 0; n < 2; ++n) {
                    f32x4 y;
                    UR for (int r = 0; r < 4; ++r)
                        y[r] = (x[m][n][r] - mean[n]) * rstd[n] * gf[m][r] + bfr_[m][r];
                    *(uint2*)((char*)Ybuf + swz(rr[n], dd[m] * 2)) = pack4(y);
                  }
            }
            if (lay > 0 && kk == 0) { WAITV10; } else { WAITV2; }
            BARRIER;                                           // (b) slice S + Y in LDS
            const unsigned short* bufp = WSH + (S & 1) * 8192;
            bf16x8 a[4], b[2];
            UR for (int m = 0; m < 4; ++m) a[m] = *(const bf16x8*)(bufp + aoff[m]);
            UR for (int n = 0; n < 2; ++n)
                b[n] = *(const bf16x8*)((const char*)Ybuf + swz(rr[n], kk * 64 + lh * 16));
            UR for (int m = 0; m < 4; ++m)
              UR for (int n = 0; n < 2; ++n)
                acc[m][n] = __builtin_amdgcn_mfma_f32_16x16x32_bf16(a[m], b[n], acc[m][n], 0, 0, 0);
        }

        // ReLU(acc + b1) -> packed H in regs
        f32x4 b1f[4];
        UR for (int m = 0; m < 4; ++m) b1f[m] = *(const f32x4*)(B1 + lay * 256 + dd[m]);
        uint2 hp[4][2];
        UR for (int m = 0; m < 4; ++m)
          UR for (int n = 0; n < 2; ++n) {
            f32x4 h;
            UR for (int r = 0; r < 4; ++r) h[r] = fmaxf(acc[m][n][r] + b1f[m][r], 0.f);
            hp[m][n] = pack4(h);
            acc[m][n] = (f32x4){0.f, 0.f, 0.f, 0.f};
          }

        // ---------- GEMM2: 8 weight slices ----------
        UR for (int kk = 0; kk < 8; ++kk) {
            int S = lay * 16 + 8 + kk;
            BARRIER;                                           // (a)
            if (S < 47) stage_slice(Wst + (S + 1) * 8192, WSH + ((S + 1) & 1) * 8192, t);
            if (kk == 0) {
                UR for (int m = 0; m < 4; ++m)
                  UR for (int n = 0; n < 2; ++n)
                    *(uint2*)((char*)Ybuf + swz(rr[n], dd[m] * 2)) = hp[m][n];
            }
            if (S == 47) { WAITV0; } else { WAITV2; }
            BARRIER;                                           // (b)
            const unsigned short* bufp = WSH + (S & 1) * 8192;
            bf16x8 a[4], b[2];
            UR for (int m = 0; m < 4; ++m) a[m] = *(const bf16x8*)(bufp + aoff[m]);
            UR for (int n = 0; n < 2; ++n)
                b[n] = *(const bf16x8*)((const char*)Ybuf + swz(rr[n], kk * 64 + lh * 16));
            UR for (int m = 0; m < 4; ++m)
              UR for (int n = 0; n < 2; ++n)
                acc[m][n] = __builtin_amdgcn_mfma_f32_16x16x32_bf16(a[m], b[n], acc[m][n], 0, 0, 0);
        }

        // residual update + store layer output (and duplicate final)
        f32x4 b2f[4];
        UR for (int m = 0; m < 4; ++m) b2f[m] = *(const f32x4*)(B2 + lay * 256 + dd[m]);
        UR for (int m = 0; m < 4; ++m)
          UR for (int n = 0; n < 2; ++n)
            UR for (int r = 0; r < 4; ++r)
                x[m][n][r] += acc[m][n][r] + b2f[m][r];

        float* outL = out + ((size_t)lay * 32768 + r0) * 512 + br * 256;
        UR for (int m = 0; m < 4; ++m)
          UR for (int n = 0; n < 2; ++n) {
            float* p = outL + (size_t)rr[n] * 512 + dd[m];
            *(f32x4*)p = x[m][n];
            if (lay == 2) *(f32x4*)(p + 16777216) = x[m][n];
          }
    }
}

extern "C" void kernel_launch(void* const* d_in, const int* in_sizes, int n_in,
                              void* d_out, int out_size, void* d_ws, size_t ws_size,
                              hipStream_t stream)
{
    const float* inputs = (const float*)d_in[0];
    const float* lpad = (const float*)d_in[1];
    const float* rpad = (const float*)d_in[2];
    const float* lwt  = (const float*)d_in[3];
    const float* rwt  = (const float*)d_in[4];
    const float* lw1  = (const float*)d_in[5];
    const float* lb1  = (const float*)d_in[6];
    const float* lw2  = (const float*)d_in[7];
    const float* lb2  = (const float*)d_in[8];
    const float* lg   = (const float*)d_in[9];
    const float* lbb  = (const float*)d_in[10];
    const float* rw1  = (const float*)d_in[11];
    const float* rb1  = (const float*)d_in[12];
    const float* rw2  = (const float*)d_in[13];
    const float* rb2  = (const float*)d_in[14];
    const float* rg   = (const float*)d_in[15];
    const float* rbb  = (const float*)d_in[16];

    char* ws = (char*)d_ws;
    // ws map: [0, 32M) conv bf16 (L then R) | [32M, +1.5M) weight stream
    unsigned short* convb = (unsigned short*)ws;
    unsigned short* wstr  = (unsigned short*)(ws + 33554432);

    prep_kernel<<<96, 256, 0, stream>>>(lw1, rw1, lw2, rw2, wstr);
    conv_kernel<<<1024, 256, 0, stream>>>(inputs, lpad, rpad, lwt, rwt,
                                          (uint2*)convb, (uint2*)(convb + 32768u * 256u));
    mega_kernel<<<1024, 512, 0, stream>>>(convb, wstr,
                                          lb1, rb1, lb2, rb2, lg, rg, lbb, rbb,
                                          (float*)d_out);
}